// Round 7
// baseline (69.332 us; speedup 1.0000x reference)
//
#include <hip/hip_runtime.h>

// Problem constants
#define NB     16384
#define NJ     14
#define NCOL   14
#define NPIX   196             // 14*14 == 49 float4
#define NTASKS (NB * NJ)       // 229376
#define BLOCK  128
#define TPG    32              // tasks per group
#define NGRP   4               // groups per block
#define TPB    (TPG * NGRP)    // 128 tasks per block
#define NBLK   (NTASKS / TPB)  // 1792 blocks = exactly 7 per CU
#define ST4    51              // LDS f4 stride per task row (204 floats; 12tl+17s+c -> 2-way banks = free)
#define GF4    (TPG * 49)      // 1568 float4 staged per group

typedef float f4 __attribute__((ext_vector_type(4)));

__global__ __launch_bounds__(BLOCK) void mse2_main(
    const float* __restrict__ osp,   // [B, 2*NJ, 196]
    const float* __restrict__ h,     // [B, NJ, 196]
    const float* __restrict__ t,     // [B, NJ, 2]
    const float* __restrict__ v,     // [B, NJ, 2]
    double* __restrict__ partials)   // [NBLK*2]
{
    __shared__ float tbl[NPIX];           // tbl[p*14+o]: 1-D gaussian response (delta at p, output o)
    __shared__ float rmax[NCOL];          // per-row max (row min is exactly 0: 9-tap support < 14)
    __shared__ float gxst[TPG * NCOL];    // per-task x-row, scaled by inv and visibility
    __shared__ float hbuf[TPG * ST4 * 4]; // 32 tasks x 204 floats
    __shared__ double sred[4];

    const int tid = threadIdx.x;
    const int blk = blockIdx.x;

    // ---- 14x14 separable-gaussian table (taps hardcoded: exact doubles of exp(-0.5 d^2)) ----
    {
        const double KDA[5] = {1.0, 0.6065306597126334, 0.1353352832366127,
                               0.011108996538242306, 0.00033546262790251185};
        double kd[9];
        double ks = 0.0;
        #pragma unroll
        for (int d = 0; d < 9; ++d) { kd[d] = KDA[d < 4 ? 4 - d : d - 4]; ks += kd[d]; }
        for (int e = tid; e < NPIX; e += BLOCK) {
            const int p = e / NCOL, o = e % NCOL;
            float s = 0.f;
            #pragma unroll
            for (int d = 0; d < 9; ++d) {
                const int i = o + d;                               // padded index 0..21
                const int m = (i < 4) ? (3 - i)                    // symmetric reflect left
                            : (i < 18) ? (i - 4)
                            : (31 - i);                            // reflect right
                if (m == p) s += (float)(kd[d] / ks);
            }
            tbl[e] = s;
        }
    }
    __syncthreads();
    if (tid < NCOL) {
        float mx = tbl[tid * NCOL];
        for (int o = 1; o < NCOL; ++o) mx = fmaxf(mx, tbl[tid * NCOL + o]);
        rmax[tid] = mx;
    }
    // (rmax first used after the staging __syncthreads below)

    const int tl = tid >> 2;      // task-local 0..31
    const int s  = tid & 3;       // segment 0..3 (49 elements each)
    const int x0 = (7 * s) % 14;  // {0,7,0,7}
    const int y0 = (49 * s) / 14; // {0,3,7,10}

    double pd = 0.0, pn = 0.0;
    float st_mval[NGRP]; int st_midx[NGRP];
    float st_t0[NGRP], st_t1[NGRP]; int st_vis[NGRP];

    const f4* __restrict__ h4 = reinterpret_cast<const f4*>(h);
    f4* __restrict__ hbuf4 = reinterpret_cast<f4*>(hbuf);

    #pragma unroll
    for (int g = 0; g < NGRP; ++g) {
        const int tbase = blk * TPB + g * TPG;
        __syncthreads();   // protect hbuf/gxst reuse from previous group's readers

        // ---- stage 32 h-rows, fully coalesced (1568 f4 / 128 threads) ----
        const size_t gbase = (size_t)tbase * 49;   // f4 units
        #pragma unroll
        for (int i = 0; i < 13; ++i) {
            const int j = tid + BLOCK * i;         // 0..1663, use j<1568
            if (j < GF4) {
                const f4 val = h4[gbase + j];
                const int tk = j / 49;             // compiler magic-div
                const int e  = j - tk * 49;
                hbuf4[tk * ST4 + e] = val;
            }
        }

        // ---- per-task scalars (4 threads redundantly; same cache lines) ----
        const int task = tbase + tl;
        const float2 tv = reinterpret_cast<const float2*>(t)[task];
        const float v0 = reinterpret_cast<const float2*>(v)[task].x;
        const bool vis = ((int)v0) == 1;
        const int xi = min(13, max(0, (int)(tv.x * 14.f)));
        const int yi = min(13, max(0, (int)(tv.y * 14.f)));
        if (s == 0) {
            const float inv = 1.f / (rmax[yi] * rmax[xi]);  // min of outer product == 0 exactly
            #pragma unroll
            for (int o = 0; o < NCOL; ++o)
                gxst[tl * NCOL + o] = vis ? tbl[xi * NCOL + o] * inv : 0.f;
        }
        __syncthreads();

        // ---- compute this thread's 49-element segment from LDS ----
        const float* __restrict__ hseg = hbuf + tl * (ST4 * 4) + s * 49;
        const float* __restrict__ gx   = gxst + tl * NCOL;
        int x = x0, y = y0;
        float gy = tbl[yi * NCOL + y];
        float mval = -1.f; int midx = 0;
        float acc = 0.f;
        const bool zmask = (s == 0) && !vis;   // row-0-of-diff zeroed when invisible

        #pragma unroll
        for (int c = 0; c < 49; ++c) {
            const float hv = hseg[c];
            const int el = s * 49 + c;
            if (hv > mval) { mval = hv; midx = el; }   // ascending el => first-occurrence
            const float d = hv - gy * gx[x];
            float cc = d * d;
            if (c < 14) { if (zmask) cc = 0.f; }       // y==0 iff s==0 && c<14
            acc += cc;
            ++x;
            if (x == NCOL) { x = 0; ++y; if (c < 48) gy = tbl[yi * NCOL + y]; }
        }

        // ---- combine across the 4 segment-lanes (4tl+s consecutive) ----
        #pragma unroll
        for (int off = 1; off <= 2; off <<= 1) {
            const float ov = __shfl_xor(mval, off);
            const int   oi = __shfl_xor(midx, off);
            const float oa = __shfl_xor(acc, off);
            acc += oa;
            if (ov > mval || (ov == mval && oi < midx)) { mval = ov; midx = oi; }
        }
        if (s == 0) {
            pd += (double)acc;
            if (vis) pn += (double)v0;    // == 1
        }
        st_mval[g] = mval; st_midx[g] = midx;
        st_t0[g] = tv.x;  st_t1[g] = tv.y; st_vis[g] = vis ? 1 : 0;
    }

    // ---- deferred d2: batch the os_ gathers for all 4 groups (leaders only) ----
    if (s == 0) {
        #pragma unroll
        for (int g = 0; g < NGRP; ++g) {
            if (st_vis[g]) {
                const int task = blk * TPB + g * TPG + tl;
                const int midx = st_midx[g];
                const int yC = midx / NCOL;
                const int xC = midx - yC * NCOL;
                const int b  = task / NJ;
                const int j  = task - b * NJ;
                const float* __restrict__ ob = osp + ((size_t)b * (2 * NJ) + j) * NPIX;
                const float osx = ob[midx];
                const float osy = ob[(size_t)NJ * NPIX + midx];
                const bool cond = st_mval[g] > 0.5f;
                const float sc = 1.0f / 14.f;
                const float xx0 = cond ? (osx + (float)xC) * sc : 0.f;
                const float xx1 = cond ? (osy + (float)yC) * sc : 0.f;
                const float dx = xx0 - st_t0[g];
                const float dy = xx1 - st_t1[g];
                pd += (double)(dx * dx + dy * dy);
            }
        }
    }

    // ---- block reduction: full-wave butterfly (non-leaders hold 0), then LDS ----
    #pragma unroll
    for (int off = 1; off < 64; off <<= 1) {
        pd += __shfl_xor(pd, off);
        pn += __shfl_xor(pn, off);
    }
    if ((tid & 63) == 0) { sred[(tid >> 6) * 2] = pd; sred[(tid >> 6) * 2 + 1] = pn; }
    __syncthreads();
    if (tid == 0) {
        partials[blk * 2 + 0] = sred[0] + sred[2];
        partials[blk * 2 + 1] = sred[1] + sred[3];
    }
}

__global__ __launch_bounds__(256) void mse2_reduce(const double* __restrict__ partials,
                                                   float* __restrict__ out)
{
    __shared__ double ssum[256], snum[256];
    double sv = 0.0, n = 0.0;
    for (int i = threadIdx.x; i < NBLK; i += 256) {
        sv += partials[i * 2 + 0];
        n  += partials[i * 2 + 1];
    }
    ssum[threadIdx.x] = sv;
    snum[threadIdx.x] = n;
    __syncthreads();
    for (int off = 128; off; off >>= 1) {
        if (threadIdx.x < off) {
            ssum[threadIdx.x] += ssum[threadIdx.x + off];
            snum[threadIdx.x] += snum[threadIdx.x + off];
        }
        __syncthreads();
    }
    if (threadIdx.x == 0) out[0] = (float)(ssum[0] / snum[0]);
}

extern "C" void kernel_launch(void* const* d_in, const int* in_sizes, int n_in,
                              void* d_out, int out_size, void* d_ws, size_t ws_size,
                              hipStream_t stream) {
    const float* osp = (const float*)d_in[0];
    const float* h   = (const float*)d_in[1];
    // d_in[2] = op, unused by the reference
    const float* t   = (const float*)d_in[3];
    const float* v   = (const float*)d_in[4];
    double* partials = (double*)d_ws;      // NBLK*2*8 = 28,672 B
    float* out = (float*)d_out;

    mse2_main<<<NBLK, BLOCK, 0, stream>>>(osp, h, t, v, partials);
    mse2_reduce<<<1, 256, 0, stream>>>(partials, out);
}

// Round 8
// 43.568 us; speedup vs baseline: 1.5913x; 1.5913x over previous
//
#include <hip/hip_runtime.h>
#include <math.h>

// Problem constants
#define NB     16384
#define NJOINT 14
#define NCOL   14
#define NPIX   196            // 14*14 == 49 float4 exactly
#define NTASKS (NB * NJOINT)  // 229376
#define RAD    4

#define BLOCK1 256
#define GRID1  (NTASKS / BLOCK1)   // 896 blocks

typedef float f4 __attribute__((ext_vector_type(4)));

__global__ __launch_bounds__(BLOCK1) void mse2_main(
    const float* __restrict__ osp,   // [B, 2*NJ, 196]
    const float* __restrict__ h,     // [B, NJ, 196]
    const float* __restrict__ t,     // [B, NJ, 2]
    const float* __restrict__ v,     // [B, NJ, 2]
    double* __restrict__ partials)   // [GRID1*2]
{
    __shared__ float tbl[NPIX];      // tbl[p*14+o]: 1-D gaussian response, delta at p, output o
    __shared__ float rmax[NCOL];     // row max (row min is exactly 0: 9-tap support < 14)
    __shared__ double sd[BLOCK1], sn[BLOCK1];

    const int tid = threadIdx.x;

    // ---- build the 14x14 separable-gaussian table once per block ----
    if (tid < NPIX) {
        // normalized gaussian taps, computed once (double, like reference)
        double kd[2 * RAD + 1];
        double ks = 0.0;
        #pragma unroll
        for (int d = 0; d <= 2 * RAD; ++d) {
            double xx = (double)(d - RAD);
            kd[d] = exp(-0.5 * xx * xx);
            ks += kd[d];
        }
        const int p = tid / NCOL, o = tid % NCOL;
        float s = 0.f;
        #pragma unroll
        for (int d = 0; d <= 2 * RAD; ++d) {
            int i = o + d;                                     // padded index 0..21
            int m = (i < RAD) ? (RAD - 1 - i)                  // symmetric reflect left
                  : (i < RAD + NCOL) ? (i - RAD)
                  : (2 * (RAD + NCOL) - 1 - i - RAD);          // 31 - i
            if (m == p) s += (float)(kd[d] / ks);
        }
        tbl[p * NCOL + o] = s;
    }
    __syncthreads();
    if (tid < NCOL) {
        float mxv = tbl[tid * NCOL];
        for (int o = 1; o < NCOL; ++o) mxv = fmaxf(mxv, tbl[tid * NCOL + o]);
        rmax[tid] = mxv;
    }
    __syncthreads();

    // ---- one task per thread ----
    const int task = blockIdx.x * BLOCK1 + tid;   // always < NTASKS (exact fit)

    const float2 tv = reinterpret_cast<const float2*>(t)[task];
    const float t0 = tv.x;
    const float t1 = tv.y;
    const float v0 = reinterpret_cast<const float2*>(v)[task].x;
    const bool vis = ((int)v0) == 1;
    const float visf = vis ? 1.f : 0.f;

    // splat center (trunc + clip, matches reference)
    const int xi = min(NCOL - 1, max(0, (int)(t0 * (float)NCOL)));
    const int yi = min(NCOL - 1, max(0, (int)(t1 * (float)NCOL)));
    const float inv = 1.f / (rmax[yi] * rmax[xi]);   // min of outer product == 0 exactly

    // gaussian rows in registers; fold inv + visibility into the x-row
    float gys[NCOL], gxs[NCOL];
    #pragma unroll
    for (int k = 0; k < NCOL; ++k) {
        gys[k] = tbl[yi * NCOL + k];
        gxs[k] = vis ? tbl[xi * NCOL + k] * inv : 0.f;
    }

    const f4* __restrict__ hb4 =
        reinterpret_cast<const f4*>(h + (size_t)task * NPIX);

    float acc  = 0.f;    // d1 partial
    float mval = -1.f;
    int   midx = 0;

    #pragma unroll
    for (int q = 0; q < NPIX / 4; ++q) {
        const f4 hv4 = hb4[q];
        #pragma unroll
        for (int j = 0; j < 4; ++j) {
            const int el = 4 * q + j;            // compile-time constant
            const int y = el / NCOL;             // compile-time
            const int x = el - y * NCOL;         // compile-time
            const float hv = hv4[j];
            // first-occurrence argmax (ascending el)
            if (hv > mval) { mval = hv; midx = el; }
            const float tgt = gys[y] * gxs[x];   // == gn (visible) or 0 (invisible)
            const float d   = hv - tgt;
            const float c   = d * d;
            // invisible: row 0 of diff zeroed (visf=0); visible: full
            acc += (y == 0) ? visf * c : c;
        }
    }

    // d2 + N contribution (per-thread)
    float d2v = 0.f, nv = 0.f;
    if (vis) {
        nv = v0;   // == 1
        const int yC = midx / NCOL;
        const int xC = midx - yC * NCOL;
        const int b  = task / NJOINT;
        const int j  = task - b * NJOINT;
        const float* __restrict__ ob = osp + ((size_t)b * (2 * NJOINT) + j) * NPIX;
        const float osx = ob[midx];
        const float osy = ob[(size_t)NJOINT * NPIX + midx];
        const bool cond = mval > 0.5f;
        const float sc = 1.0f / (float)NCOL;
        const float x0 = cond ? (osx + (float)xC) * sc : 0.f;
        const float x1 = cond ? (osy + (float)yC) * sc : 0.f;
        const float dx = x0 - t0;
        const float dy = x1 - t1;
        d2v = dx * dx + dy * dy;
    }

    // ---- deterministic block reduction (doubles) ----
    sd[tid] = (double)acc + (double)d2v;
    sn[tid] = (double)nv;
    __syncthreads();
    #pragma unroll
    for (int off = BLOCK1 / 2; off > 0; off >>= 1) {
        if (tid < off) {
            sd[tid] += sd[tid + off];
            sn[tid] += sn[tid + off];
        }
        __syncthreads();
    }
    if (tid == 0) {
        partials[blockIdx.x * 2 + 0] = sd[0];
        partials[blockIdx.x * 2 + 1] = sn[0];
    }
}

__global__ __launch_bounds__(256) void mse2_reduce(const double* __restrict__ partials,
                                                   float* __restrict__ out)
{
    __shared__ double ssum[256], snum[256];
    const double2* __restrict__ p2 = reinterpret_cast<const double2*>(partials);
    double s = 0.0, n = 0.0;
    for (int i = threadIdx.x; i < GRID1; i += 256) {
        const double2 pv = p2[i];          // 16B load: {sum, count} for block i
        s += pv.x;
        n += pv.y;
    }
    ssum[threadIdx.x] = s;
    snum[threadIdx.x] = n;
    __syncthreads();
    for (int off = 128; off; off >>= 1) {
        if (threadIdx.x < off) {
            ssum[threadIdx.x] += ssum[threadIdx.x + off];
            snum[threadIdx.x] += snum[threadIdx.x + off];
        }
        __syncthreads();
    }
    if (threadIdx.x == 0) out[0] = (float)(ssum[0] / snum[0]);
}

extern "C" void kernel_launch(void* const* d_in, const int* in_sizes, int n_in,
                              void* d_out, int out_size, void* d_ws, size_t ws_size,
                              hipStream_t stream) {
    const float* osp = (const float*)d_in[0];
    const float* h   = (const float*)d_in[1];
    // d_in[2] = op, unused by the reference
    const float* t   = (const float*)d_in[3];
    const float* v   = (const float*)d_in[4];
    double* partials = (double*)d_ws;
    float* out = (float*)d_out;

    mse2_main<<<GRID1, BLOCK1, 0, stream>>>(osp, h, t, v, partials);
    mse2_reduce<<<1, 256, 0, stream>>>(partials, out);
}